// Round 2
// baseline (241.812 us; speedup 1.0000x reference)
//
#include <hip/hip_runtime.h>

// SeaThru-NeRF RGB renderer forward pass, round 2.
// One wave (64 lanes) per ray; lane t owns samples 4t..4t+3 (12 consecutive
// floats of each [S,3] row). 3-channel arrays are loaded COALESCED (lane t
// reads float4 chunks t, t+64, t+128 => 1024B contiguous per instruction),
// then transposed to sample-major via a per-wave padded LDS buffer.
// Padding: word address = g + (g>>5)  (one pad word per 32) -> <=2-way bank
// aliasing on both write and read sides (free on CDNA4 per m136).

__device__ __forceinline__ float clip01(float x) {
    return fminf(fmaxf(x, 0.0f), 1.0f);
}

__device__ __forceinline__ float wave_exscan(float v, int lane) {
    float x = v;
#pragma unroll
    for (int off = 1; off < 64; off <<= 1) {
        float y = __shfl_up(x, off, 64);
        x += (lane >= off) ? y : 0.0f;
    }
    return x - v;  // inclusive -> exclusive
}

__device__ __forceinline__ float wave_sum(float v) {
#pragma unroll
    for (int off = 32; off; off >>= 1) v += __shfl_xor(v, off, 64);
    return v;
}

#define PADIDX(g) ((g) + ((g) >> 5))

// Coalesced chunks -> sample-major 12 floats per lane, via per-wave LDS.
// Same-wave DS ops are processed in order; wave_barrier pins compiler order.
__device__ __forceinline__ void transpose12(float* __restrict__ lds, int lane,
                                            float4 c0, float4 c1, float4 c2,
                                            float out[12]) {
    const int g0 = 4 * lane;          // chunk 0: floats [0,256)
    lds[PADIDX(g0 + 0)] = c0.x; lds[PADIDX(g0 + 1)] = c0.y;
    lds[PADIDX(g0 + 2)] = c0.z; lds[PADIDX(g0 + 3)] = c0.w;
    const int g1 = 256 + 4 * lane;    // chunk 1: floats [256,512)
    lds[PADIDX(g1 + 0)] = c1.x; lds[PADIDX(g1 + 1)] = c1.y;
    lds[PADIDX(g1 + 2)] = c1.z; lds[PADIDX(g1 + 3)] = c1.w;
    const int g2 = 512 + 4 * lane;    // chunk 2: floats [512,768)
    lds[PADIDX(g2 + 0)] = c2.x; lds[PADIDX(g2 + 1)] = c2.y;
    lds[PADIDX(g2 + 2)] = c2.z; lds[PADIDX(g2 + 3)] = c2.w;
    __builtin_amdgcn_wave_barrier();
    const int gt = 12 * lane;         // lane t owns floats [12t, 12t+12)
#pragma unroll
    for (int j = 0; j < 12; ++j) out[j] = lds[PADIDX(gt + j)];
    __builtin_amdgcn_wave_barrier();
}

__global__ __launch_bounds__(256) void seathru_render(
    const float* __restrict__ g_orgb,   // [R,S,3]
    const float* __restrict__ g_mrgb,   // [R,S,3]
    const float* __restrict__ g_dc,     // [R,S,3]
    const float* __restrict__ g_bc,     // [R,S,3]
    const float* __restrict__ g_den,    // [R,S,1]
    const float* __restrict__ g_del,    // [R,S,1]
    float* __restrict__ out, int R)
{
    const int S = 256;
    const int wv   = threadIdx.x >> 6;
    const int lane = threadIdx.x & 63;
    const int ray  = blockIdx.x * 4 + wv;
    if (ray >= R) return;

    __shared__ float lds_all[4][792];   // 768 + 768/32 pad words, per wave
    float* lds = lds_all[wv];

    const size_t b3 = (size_t)ray * (S * 3);
    const size_t b1 = (size_t)ray * S;
    const size_t RS = (size_t)R * S;

    // ---- coalesced global loads: 3x float4 per lane per 3ch array ----
    const float4* po = (const float4*)(g_orgb + b3);
    const float4* pm = (const float4*)(g_mrgb + b3);
    const float4* pd = (const float4*)(g_dc + b3);
    const float4* pb = (const float4*)(g_bc + b3);
    float4 o0 = po[lane], o1 = po[lane + 64], o2 = po[lane + 128];
    float4 m0 = pm[lane], m1 = pm[lane + 64], m2 = pm[lane + 128];
    float4 d0 = pd[lane], d1 = pd[lane + 64], d2 = pd[lane + 128];
    float4 bb0 = pb[lane], bb1 = pb[lane + 64], bb2 = pb[lane + 128];
    float4 dl4 = *((const float4*)(g_del + b1) + lane);
    float4 dn4 = *((const float4*)(g_den + b1) + lane);

    // ---- LDS transpose to sample-major (12 consecutive floats / lane) ----
    float orv[12], mrv[12], dcv[12], bcv[12];
    transpose12(lds, lane, o0, o1, o2, orv);
    transpose12(lds, lane, m0, m1, m2, mrv);
    transpose12(lds, lane, d0, d1, d2, dcv);
    transpose12(lds, lane, bb0, bb1, bb2, bcv);

    float del[4] = {dl4.x, dl4.y, dl4.z, dl4.w};
    float den[4] = {dn4.x, dn4.y, dn4.z, dn4.w};

    // ---- object transmittance / alpha / weights ----
    float dd[4], ex_dd[4];
    float run = 0.0f;
#pragma unroll
    for (int i = 0; i < 4; ++i) { dd[i] = del[i] * den[i]; ex_dd[i] = run; run += dd[i]; }
    const float off_dd = wave_exscan(run, lane);

    float T[4], alpha[4], w[4];
#pragma unroll
    for (int i = 0; i < 4; ++i) {
        T[i]     = __expf(-(off_dd + ex_dd[i]));
        alpha[i] = 1.0f - __expf(-dd[i]);
        w[i]     = T[i] * alpha[i];
    }

    // ---- per-sample outputs (coalesced float4 stores) ----
    float* outT = out + (size_t)12 * R;
    float* outA = outT + RS;
    float* outW = outA + RS;
    {
        float4 t4 = {T[0], T[1], T[2], T[3]};
        float4 a4 = {alpha[0], alpha[1], alpha[2], alpha[3]};
        float4 w4 = {w[0], w[1], w[2], w[3]};
        *((float4*)(outT + b1) + lane) = t4;
        *((float4*)(outA + b1) + lane) = a4;
        *((float4*)(outW + b1) + lane) = w4;
    }

    // ---- per-channel direct / backscatter scans + weighted sums ----
    float acc_dir[3], acc_bs[3], acc_rest[3];
    float acc_mask = w[0] + w[1] + w[2] + w[3];

#pragma unroll
    for (int c = 0; c < 3; ++c) {
        float dcd[4], exd[4], rund = 0.0f;
#pragma unroll
        for (int i = 0; i < 4; ++i) { dcd[i] = dcv[i * 3 + c] * del[i]; exd[i] = rund; rund += dcd[i]; }
        const float offd = wave_exscan(rund, lane);

        float ad = 0.0f, ar = 0.0f;
#pragma unroll
        for (int i = 0; i < 4; ++i) {
            const float da = __expf(-(offd + exd[i]));
            const float o  = orv[i * 3 + c];
            ad += T[i] * da * alpha[i] * o;
            ar += w[i] * o;
        }
        acc_dir[c] = ad;
        acc_rest[c] = ar;

        float bsd[4], exb[4], runb = 0.0f;
#pragma unroll
        for (int i = 0; i < 4; ++i) { bsd[i] = bcv[i * 3 + c] * del[i]; exb[i] = runb; runb += bsd[i]; }
        const float offb = wave_exscan(runb, lane);

        float ab = 0.0f;
#pragma unroll
        for (int i = 0; i < 4; ++i) {
            const float B  = __expf(-(offb + exb[i]));
            const float ma = 1.0f - __expf(-bsd[i]);
            ab += T[i] * B * ma * mrv[i * 3 + c];
        }
        acc_bs[c] = ab;
    }

    // ---- wave reductions ----
#pragma unroll
    for (int c = 0; c < 3; ++c) {
        acc_dir[c]  = wave_sum(acc_dir[c]);
        acc_bs[c]   = wave_sum(acc_bs[c]);
        acc_rest[c] = wave_sum(acc_rest[c]);
    }
    acc_mask = wave_sum(acc_mask);

    // ---- per-ray outputs (lane 0) ----
    if (lane == 0) {
        float* rgb  = out;
        float* rest = out + (size_t)3 * R;
        float* dir  = out + (size_t)6 * R;
        float* bs   = out + (size_t)9 * R;
        float* dc0  = out + (size_t)12 * R + 3 * RS;
        float* bc0  = dc0 + (size_t)3 * R;
        float* mask = bc0 + (size_t)3 * R;
#pragma unroll
        for (int c = 0; c < 3; ++c) {
            const float d = acc_dir[c], b = acc_bs[c];
            rgb[ray * 3 + c]  = clip01(d + b);
            rest[ray * 3 + c] = clip01(acc_rest[c]);
            dir[ray * 3 + c]  = clip01(d);
            bs[ray * 3 + c]   = clip01(b);
            dc0[ray * 3 + c]  = dcv[c];   // lane 0, sample 0, channel c
            bc0[ray * 3 + c]  = bcv[c];
        }
        mask[ray] = clip01(acc_mask);
    }
}

extern "C" void kernel_launch(void* const* d_in, const int* in_sizes, int n_in,
                              void* d_out, int out_size, void* d_ws, size_t ws_size,
                              hipStream_t stream) {
    const float* orgb = (const float*)d_in[0];
    const float* mrgb = (const float*)d_in[1];
    const float* dc   = (const float*)d_in[2];
    const float* bc   = (const float*)d_in[3];
    const float* den  = (const float*)d_in[4];
    const float* del  = (const float*)d_in[5];

    const int S = 256;
    const int R = in_sizes[0] / (S * 3);

    dim3 block(256);                 // 4 waves = 4 rays per block
    dim3 grid((R + 3) / 4);
    seathru_render<<<grid, block, 0, stream>>>(orgb, mrgb, dc, bc, den, del,
                                               (float*)d_out, R);
}

// Round 3
// 239.543 us; speedup vs baseline: 1.0095x; 1.0095x over previous
//
#include <hip/hip_runtime.h>

// SeaThru-NeRF RGB renderer forward pass, round 3.
// One wave (64 lanes) per ray; lane t owns samples 4t..4t+3 (12 consecutive
// floats of each [S,3] row, loaded as 3 float4 at 48B lane stride -- L2
// absorbs the line-level overfetch; HBM bytes are near-ideal per R1 rocprof).
//
// KEY CHANGE vs R1/R2: __launch_bounds__(256, 2) lifts the VGPR cap to 256.
// R1/R2 compiled at 40/52 VGPRs -- far below the ~100+ live floats -- forcing
// scratch spill/fill round-trips that dominated wave lifetime (96us with all
// pipes <25% busy). Loads are issued in consumption order so vmcnt retires
// progressively. No LDS.

__device__ __forceinline__ float clip01(float x) {
    return fminf(fmaxf(x, 0.0f), 1.0f);
}

// Exclusive prefix sum across the 64-lane wave.
__device__ __forceinline__ float wave_exscan(float v, int lane) {
    float x = v;
#pragma unroll
    for (int off = 1; off < 64; off <<= 1) {
        float y = __shfl_up(x, off, 64);
        x += (lane >= off) ? y : 0.0f;
    }
    return x - v;  // inclusive -> exclusive
}

__device__ __forceinline__ float wave_sum(float v) {
#pragma unroll
    for (int off = 32; off; off >>= 1) v += __shfl_xor(v, off, 64);
    return v;
}

__global__ __launch_bounds__(256, 2) void seathru_render(
    const float* __restrict__ g_orgb,   // [R,S,3] object_rgbs
    const float* __restrict__ g_mrgb,   // [R,S,3] medium_rgbs
    const float* __restrict__ g_dc,     // [R,S,3] direct_coeffs
    const float* __restrict__ g_bc,     // [R,S,3] backscatter_coeffs
    const float* __restrict__ g_den,    // [R,S,1] densities
    const float* __restrict__ g_del,    // [R,S,1] deltas
    float* __restrict__ out, int R)
{
    const int S = 256;
    const int ray  = blockIdx.x * 4 + (threadIdx.x >> 6);
    const int lane = threadIdx.x & 63;
    if (ray >= R) return;

    const size_t b3 = (size_t)ray * (S * 3);
    const size_t b1 = (size_t)ray * S;
    const size_t RS = (size_t)R * S;

    // ---- issue ALL loads up front, in consumption order ----
    float4 dl4 = *((const float4*)(g_del + b1) + lane);
    float4 dn4 = *((const float4*)(g_den + b1) + lane);

    float dcv[12], orv[12], bcv[12], mrv[12];
    {
        const float4* p = (const float4*)(g_dc + b3) + lane * 3;
        *(float4*)&dcv[0] = p[0]; *(float4*)&dcv[4] = p[1]; *(float4*)&dcv[8] = p[2];
    }
    {
        const float4* p = (const float4*)(g_orgb + b3) + lane * 3;
        *(float4*)&orv[0] = p[0]; *(float4*)&orv[4] = p[1]; *(float4*)&orv[8] = p[2];
    }
    {
        const float4* p = (const float4*)(g_bc + b3) + lane * 3;
        *(float4*)&bcv[0] = p[0]; *(float4*)&bcv[4] = p[1]; *(float4*)&bcv[8] = p[2];
    }
    {
        const float4* p = (const float4*)(g_mrgb + b3) + lane * 3;
        *(float4*)&mrv[0] = p[0]; *(float4*)&mrv[4] = p[1]; *(float4*)&mrv[8] = p[2];
    }

    float del[4] = {dl4.x, dl4.y, dl4.z, dl4.w};
    float den[4] = {dn4.x, dn4.y, dn4.z, dn4.w};

    // ---- object transmittance / alpha / weights (needs only del/den) ----
    float dd[4], ex_dd[4];
    float run = 0.0f;
#pragma unroll
    for (int i = 0; i < 4; ++i) { dd[i] = del[i] * den[i]; ex_dd[i] = run; run += dd[i]; }
    const float off_dd = wave_exscan(run, lane);

    float T[4], alpha[4], w[4];
#pragma unroll
    for (int i = 0; i < 4; ++i) {
        T[i]     = __expf(-(off_dd + ex_dd[i]));
        alpha[i] = 1.0f - __expf(-dd[i]);
        w[i]     = T[i] * alpha[i];
    }

    // ---- per-sample outputs (coalesced float4 stores) ----
    float* outT = out + (size_t)12 * R;       // object_transmittance [R,S]
    float* outA = outT + RS;                  // object_alphas
    float* outW = outA + RS;                  // object_weights
    {
        float4 t4 = {T[0], T[1], T[2], T[3]};
        float4 a4 = {alpha[0], alpha[1], alpha[2], alpha[3]};
        float4 w4 = {w[0], w[1], w[2], w[3]};
        *((float4*)(outT + b1) + lane) = t4;
        *((float4*)(outA + b1) + lane) = a4;
        *((float4*)(outW + b1) + lane) = w4;
    }

    // ---- per-channel direct / backscatter scans + weighted sums ----
    float acc_dir[3], acc_bs[3], acc_rest[3];
    float acc_mask = w[0] + w[1] + w[2] + w[3];

#pragma unroll
    for (int c = 0; c < 3; ++c) {
        // direct attenuation channel c (consumes dcv, orv)
        float dcd[4], exd[4], rund = 0.0f;
#pragma unroll
        for (int i = 0; i < 4; ++i) { dcd[i] = dcv[i * 3 + c] * del[i]; exd[i] = rund; rund += dcd[i]; }
        const float offd = wave_exscan(rund, lane);

        float ad = 0.0f, ar = 0.0f;
#pragma unroll
        for (int i = 0; i < 4; ++i) {
            const float da = __expf(-(offd + exd[i]));
            const float o  = orv[i * 3 + c];
            ad += T[i] * da * alpha[i] * o;
            ar += w[i] * o;
        }
        acc_dir[c] = ad;
        acc_rest[c] = ar;

        // backscatter channel c (consumes bcv, mrv)
        float bsd[4], exb[4], runb = 0.0f;
#pragma unroll
        for (int i = 0; i < 4; ++i) { bsd[i] = bcv[i * 3 + c] * del[i]; exb[i] = runb; runb += bsd[i]; }
        const float offb = wave_exscan(runb, lane);

        float ab = 0.0f;
#pragma unroll
        for (int i = 0; i < 4; ++i) {
            const float B  = __expf(-(offb + exb[i]));
            const float ma = 1.0f - __expf(-bsd[i]);
            ab += T[i] * B * ma * mrv[i * 3 + c];
        }
        acc_bs[c] = ab;
    }

    // ---- wave reductions (10 scalars) ----
#pragma unroll
    for (int c = 0; c < 3; ++c) {
        acc_dir[c]  = wave_sum(acc_dir[c]);
        acc_bs[c]   = wave_sum(acc_bs[c]);
        acc_rest[c] = wave_sum(acc_rest[c]);
    }
    acc_mask = wave_sum(acc_mask);

    // ---- per-ray outputs (lane 0) ----
    if (lane == 0) {
        float* rgb  = out;                                  // [R,3]
        float* rest = out + (size_t)3 * R;                  // [R,3]
        float* dir  = out + (size_t)6 * R;                  // [R,3]
        float* bs   = out + (size_t)9 * R;                  // [R,3]
        float* dc0  = out + (size_t)12 * R + 3 * RS;        // direct_coeffs[:,0,:]
        float* bc0  = dc0 + (size_t)3 * R;                  // backscatter_coeffs[:,0,:]
        float* mask = bc0 + (size_t)3 * R;                  // [R,1]
#pragma unroll
        for (int c = 0; c < 3; ++c) {
            const float d = acc_dir[c], b = acc_bs[c];
            rgb[ray * 3 + c]  = clip01(d + b);
            rest[ray * 3 + c] = clip01(acc_rest[c]);
            dir[ray * 3 + c]  = clip01(d);
            bs[ray * 3 + c]   = clip01(b);
            dc0[ray * 3 + c]  = dcv[c];   // lane 0, sample 0, channel c
            bc0[ray * 3 + c]  = bcv[c];
        }
        mask[ray] = clip01(acc_mask);
    }
}

extern "C" void kernel_launch(void* const* d_in, const int* in_sizes, int n_in,
                              void* d_out, int out_size, void* d_ws, size_t ws_size,
                              hipStream_t stream) {
    const float* orgb = (const float*)d_in[0];
    const float* mrgb = (const float*)d_in[1];
    const float* dc   = (const float*)d_in[2];
    const float* bc   = (const float*)d_in[3];
    const float* den  = (const float*)d_in[4];
    const float* del  = (const float*)d_in[5];

    const int S = 256;
    const int R = in_sizes[0] / (S * 3);

    dim3 block(256);                 // 4 waves = 4 rays per block
    dim3 grid((R + 3) / 4);
    seathru_render<<<grid, block, 0, stream>>>(orgb, mrgb, dc, bc, den, del,
                                               (float*)d_out, R);
}